// Round 1
// 1167.284 us; speedup vs baseline: 1.1023x; 1.1023x over previous
//
#include <hip/hip_runtime.h>
#include <math.h>

#define N_NODES 50000
#define N_EDGES 800000
#define CH 128        // IN_CH = OUT_CH = MSG_DIM = TIME_DIM = 128
#define GDIM 512      // 2 heads * 256 (G per-node vector)

// ---------------------------------------------------------------------------
// build_M: M[i][f] = sum_c Wq[i][h*64+c] * We[jj][h*64+c],  f = h*256+jj
// ---------------------------------------------------------------------------
__global__ __launch_bounds__(256) void build_M_kernel(
    const float* __restrict__ Wq, const float* __restrict__ We,
    float* __restrict__ M)
{
    __shared__ float wq[CH];
    const int i = blockIdx.x, t = threadIdx.x;
    if (t < CH) wq[t] = Wq[i * CH + t];
    __syncthreads();
    #pragma unroll
    for (int rep = 0; rep < 2; ++rep) {
        int f  = rep * 256 + t;
        int h  = f >> 8, jj = f & 255;
        const float* wer = We + (size_t)jj * CH + h * 64;
        const float* wqr = wq + h * 64;
        float s = 0.f;
        #pragma unroll 8
        for (int c = 0; c < 64; ++c) s = fmaf(wqr[c], wer[c], s);
        M[(size_t)i * GDIM + f] = s;
    }
}

__global__ void build_gbias_kernel(const float* __restrict__ bq,
                                   const float* __restrict__ We,
                                   float* __restrict__ gb)
{
    int f = blockIdx.x * 256 + threadIdx.x;  // 512 total
    int h = f >> 8, jj = f & 255;
    float s = 0.f;
    #pragma unroll 8
    for (int c = 0; c < 64; ++c)
        s = fmaf(bq[h * 64 + c], We[(size_t)jj * CH + h * 64 + c], s);
    gb[f] = s;
}

// ---------------------------------------------------------------------------
// node_linear: Q,K,V,S = x@W+b (128 cols each), G = x@M+gb (512 cols).
// ---------------------------------------------------------------------------
__global__ __launch_bounds__(256) void node_linear_kernel(
    const float* __restrict__ x,
    const float* __restrict__ Wq, const float* __restrict__ bq,
    const float* __restrict__ Wk, const float* __restrict__ bk,
    const float* __restrict__ Wv, const float* __restrict__ bv,
    const float* __restrict__ Ws, const float* __restrict__ bs,
    const float* __restrict__ M,  const float* __restrict__ gb,
    float* __restrict__ Q, float* __restrict__ K,
    float* __restrict__ V, float* __restrict__ S, float* __restrict__ G)
{
    __shared__ float xs[64][CH];
    const int t  = threadIdx.x;
    const int n0 = blockIdx.x * 64;

    #pragma unroll
    for (int r = 0; r < 8; ++r) {
        int flat4 = r * 256 + t;        // float4 index in 64x128 tile
        int row   = flat4 >> 5;
        int c4    = (flat4 & 31) * 4;
        int gr    = n0 + row; if (gr >= N_NODES) gr = N_NODES - 1;
        *(float4*)&xs[row][c4] = *(const float4*)&x[(size_t)gr * CH + c4];
    }
    __syncthreads();

    const int tx = t & 31, ey = t >> 5;
    const int c0 = tx * 4, e0 = ey * 8;

    const float* Wp[8]   = {Wq, Wk, Wv, Ws, M, M + 128, M + 256, M + 384};
    const int    wstr[8] = {CH, CH, CH, CH, GDIM, GDIM, GDIM, GDIM};
    const float* Bp[8]   = {bq, bk, bv, bs, gb, gb + 128, gb + 256, gb + 384};
    float*       Op[8]   = {Q, K, V, S, G, G + 128, G + 256, G + 384};
    const int    ostr[8] = {CH, CH, CH, CH, GDIM, GDIM, GDIM, GDIM};

    #pragma unroll
    for (int m = 0; m < 8; ++m) {
        const float* W = Wp[m];
        const int ws_ = wstr[m];
        float4 acc[8];
        #pragma unroll
        for (int i = 0; i < 8; ++i) acc[i] = make_float4(0.f, 0.f, 0.f, 0.f);
        for (int j = 0; j < CH; ++j) {
            float4 w = *(const float4*)&W[(size_t)j * ws_ + c0];
            #pragma unroll
            for (int i = 0; i < 8; ++i) {
                float a = xs[e0 + i][j];
                acc[i].x = fmaf(a, w.x, acc[i].x);
                acc[i].y = fmaf(a, w.y, acc[i].y);
                acc[i].z = fmaf(a, w.z, acc[i].z);
                acc[i].w = fmaf(a, w.w, acc[i].w);
            }
        }
        float4 b4 = *(const float4*)&Bp[m][c0];
        float* O  = Op[m];
        const int os = ostr[m];
        #pragma unroll
        for (int i = 0; i < 8; ++i) {
            int n = n0 + e0 + i;
            if (n < N_NODES) {
                float4 r = make_float4(acc[i].x + b4.x, acc[i].y + b4.y,
                                       acc[i].z + b4.z, acc[i].w + b4.w);
                *(float4*)&O[(size_t)n * os + c0] = r;
            }
        }
    }
}

// ---------------------------------------------------------------------------
// counting sort of edges by destination node
// ---------------------------------------------------------------------------
__global__ void hist_kernel(const int* __restrict__ ei, int* __restrict__ cnt)
{
    int e = blockIdx.x * 256 + threadIdx.x;
    atomicAdd(&cnt[ei[N_EDGES + e]], 1);
}

__global__ __launch_bounds__(1024) void scan_kernel(
    const int* __restrict__ cnt, int* __restrict__ base, int* __restrict__ cursor)
{
    __shared__ int ssum[1024];
    const int t = threadIdx.x;
    const int STRIP = 49;  // 1024*49 = 50176 >= N_NODES
    const int s0 = t * STRIP;
    int sum = 0;
    for (int i = 0; i < STRIP; ++i) {
        int idx = s0 + i;
        sum += (idx < N_NODES) ? cnt[idx] : 0;
    }
    ssum[t] = sum;
    __syncthreads();
    for (int off = 1; off < 1024; off <<= 1) {
        int v = (t >= off) ? ssum[t - off] : 0;
        __syncthreads();
        ssum[t] += v;
        __syncthreads();
    }
    int run = (t > 0) ? ssum[t - 1] : 0;
    for (int i = 0; i < STRIP; ++i) {
        int idx = s0 + i;
        if (idx < N_NODES) {
            base[idx] = run; cursor[idx] = run;
            run += cnt[idx];
        }
    }
    if (t == 1023) base[N_NODES] = ssum[1023];
}

// scatter: also precompute rel_t per edge and fuse (src,eid) into int2 so the
// gather loop has no dependent random scalar loads on its critical path.
__global__ void scatter_kernel(const int* __restrict__ ei,
                               const float* __restrict__ last_update,
                               const float* __restrict__ t_arr,
                               int* __restrict__ cursor,
                               int2* __restrict__ sedge,
                               float* __restrict__ srt)
{
    int e = blockIdx.x * 256 + threadIdx.x;
    int s = ei[e];
    int d = ei[N_EDGES + e];
    int pos = atomicAdd(&cursor[d], 1);
    sedge[pos] = make_int2(s, e);
    srt[pos] = last_update[s] - t_arr[e];
}

// ---------------------------------------------------------------------------
// wave-wide sum broadcast to all 64 lanes.
// xor1/2/4/8 via DPP (VALU-speed), xor16 via ds_swizzle, xor32 via bpermute.
// ---------------------------------------------------------------------------
__device__ __forceinline__ float wave_allsum(float p) {
    p += __int_as_float(__builtin_amdgcn_update_dpp(
            0, __float_as_int(p), 0xB1, 0xF, 0xF, true));   // quad_perm [1,0,3,2] : xor1
    p += __int_as_float(__builtin_amdgcn_update_dpp(
            0, __float_as_int(p), 0x4E, 0xF, 0xF, true));   // quad_perm [2,3,0,1] : xor2
    p += __int_as_float(__builtin_amdgcn_update_dpp(
            0, __float_as_int(p), 0x141, 0xF, 0xF, true));  // row_half_mirror     : xor across 4
    p += __int_as_float(__builtin_amdgcn_update_dpp(
            0, __float_as_int(p), 0x140, 0xF, 0xF, true));  // row_mirror          : xor across 8 -> 16-sum
    p += __int_as_float(__builtin_amdgcn_ds_swizzle(__float_as_int(p), 0x401F)); // xor16 -> 32-sum
    p += __shfl_xor(p, 32);                                                      // xor32 -> 64-sum
    return p;
}

// ---------------------------------------------------------------------------
// gather_attn: one wave per destination node, edge loop unrolled x2 for ILP.
// Epilogue (We projection) is block-cooperative: We row loaded once per BLOCK
// (4 nodes) instead of once per wave -> 4x less L2 traffic, 4x less serial work.
// ---------------------------------------------------------------------------
__global__ __launch_bounds__(256) void gather_attn_kernel(
    const float* __restrict__ msg,
    const float* __restrict__ W_time,
    const float* __restrict__ b_time,
    const float* __restrict__ We,
    const float* __restrict__ Q, const float* __restrict__ K,
    const float* __restrict__ V, const float* __restrict__ S,
    const float* __restrict__ G,
    const int* __restrict__ base,
    const int2* __restrict__ sedge,
    const float* __restrict__ srt,
    float* __restrict__ out)
{
    __shared__ float wabuf[4][GDIM];   // p-weighted edge_attr sums, per head
    __shared__ float nvbuf[4][CH];     // p-weighted V sums
    __shared__ float dsh[4][2];        // softmax denominators per head
    __shared__ int   degsh[4];
    const int wv = threadIdx.x >> 6;
    const int j  = threadIdx.x & 63;
    const int n  = blockIdx.x * 4 + wv;

    const float q0 = Q[(size_t)n * CH + j];
    const float q1 = Q[(size_t)n * CH + 64 + j];
    const float* gn = G + (size_t)n * GDIM + j;
    const float g00 = gn[0],   g01 = gn[64],  g02 = gn[128], g03 = gn[192];
    const float g10 = gn[256], g11 = gn[320], g12 = gn[384], g13 = gn[448];
    const float wt0 = W_time[j], wt1 = W_time[64 + j];
    const float bt0 = b_time[j], bt1 = b_time[64 + j];

    float wa00 = 0.f, wa01 = 0.f, wa02 = 0.f, wa03 = 0.f;
    float wa10 = 0.f, wa11 = 0.f, wa12 = 0.f, wa13 = 0.f;
    float nv0 = 0.f, nv1 = 0.f, den0 = 0.f, den1 = 0.f;

    const int b0 = base[n], b1 = base[n + 1];
    int i = b0;

    // -------- main loop: 2 edges per iteration, loads batched up front -----
    for (; i + 2 <= b1; i += 2) {
        const int2  seA = sedge[i];
        const int2  seB = sedge[i + 1];
        const float rtA = srt[i];
        const float rtB = srt[i + 1];
        const float* mA  = msg + (size_t)seA.y * CH;
        const float* mB  = msg + (size_t)seB.y * CH;
        const float* kpA = K   + (size_t)seA.x * CH;
        const float* kpB = K   + (size_t)seB.x * CH;
        const float* vpA = V   + (size_t)seA.x * CH;
        const float* vpB = V   + (size_t)seB.x * CH;

        float ea2A = mA[j],      ea3A = mA[64 + j];
        float ea2B = mB[j],      ea3B = mB[64 + j];
        float k0A  = kpA[j],     k1A  = kpA[64 + j];
        float k0B  = kpB[j],     k1B  = kpB[64 + j];
        float v0A  = vpA[j],     v1A  = vpA[64 + j];
        float v0B  = vpB[j],     v1B  = vpB[64 + j];

        float ea0A = __cosf(fmaf(rtA, wt0, bt0));
        float ea1A = __cosf(fmaf(rtA, wt1, bt1));
        float ea0B = __cosf(fmaf(rtB, wt0, bt0));
        float ea1B = __cosf(fmaf(rtB, wt1, bt1));

        float pA0 = fmaf(q0, k0A, fmaf(ea0A, g00, fmaf(ea1A, g01, fmaf(ea2A, g02, ea3A * g03))));
        float pA1 = fmaf(q1, k1A, fmaf(ea0A, g10, fmaf(ea1A, g11, fmaf(ea2A, g12, ea3A * g13))));
        float pB0 = fmaf(q0, k0B, fmaf(ea0B, g00, fmaf(ea1B, g01, fmaf(ea2B, g02, ea3B * g03))));
        float pB1 = fmaf(q1, k1B, fmaf(ea0B, g10, fmaf(ea1B, g11, fmaf(ea2B, g12, ea3B * g13))));

        pA0 = wave_allsum(pA0);
        pA1 = wave_allsum(pA1);
        pB0 = wave_allsum(pB0);
        pB1 = wave_allsum(pB1);

        pA0 = __expf(pA0 * 0.125f);
        pA1 = __expf(pA1 * 0.125f);
        pB0 = __expf(pB0 * 0.125f);
        pB1 = __expf(pB1 * 0.125f);

        den0 += pA0; den0 += pB0;
        den1 += pA1; den1 += pB1;
        wa00 = fmaf(pA0, ea0A, wa00); wa00 = fmaf(pB0, ea0B, wa00);
        wa01 = fmaf(pA0, ea1A, wa01); wa01 = fmaf(pB0, ea1B, wa01);
        wa02 = fmaf(pA0, ea2A, wa02); wa02 = fmaf(pB0, ea2B, wa02);
        wa03 = fmaf(pA0, ea3A, wa03); wa03 = fmaf(pB0, ea3B, wa03);
        wa10 = fmaf(pA1, ea0A, wa10); wa10 = fmaf(pB1, ea0B, wa10);
        wa11 = fmaf(pA1, ea1A, wa11); wa11 = fmaf(pB1, ea1B, wa11);
        wa12 = fmaf(pA1, ea2A, wa12); wa12 = fmaf(pB1, ea2B, wa12);
        wa13 = fmaf(pA1, ea3A, wa13); wa13 = fmaf(pB1, ea3B, wa13);
        nv0  = fmaf(pA0, v0A, nv0);   nv0  = fmaf(pB0, v0B, nv0);
        nv1  = fmaf(pA1, v1A, nv1);   nv1  = fmaf(pB1, v1B, nv1);
    }

    // -------- tail: at most one edge ---------------------------------------
    if (i < b1) {
        const int2  se = sedge[i];
        const float rt = srt[i];
        const float* m  = msg + (size_t)se.y * CH;
        const float* kp = K   + (size_t)se.x * CH;
        const float* vp = V   + (size_t)se.x * CH;
        float ea2 = m[j],  ea3 = m[64 + j];
        float k0  = kp[j], k1  = kp[64 + j];
        float v0  = vp[j], v1  = vp[64 + j];
        float ea0 = __cosf(fmaf(rt, wt0, bt0));
        float ea1 = __cosf(fmaf(rt, wt1, bt1));

        float p0 = fmaf(q0, k0, fmaf(ea0, g00, fmaf(ea1, g01, fmaf(ea2, g02, ea3 * g03))));
        float p1 = fmaf(q1, k1, fmaf(ea0, g10, fmaf(ea1, g11, fmaf(ea2, g12, ea3 * g13))));
        p0 = wave_allsum(p0);
        p1 = wave_allsum(p1);
        p0 = __expf(p0 * 0.125f);
        p1 = __expf(p1 * 0.125f);

        den0 += p0; den1 += p1;
        wa00 = fmaf(p0, ea0, wa00); wa01 = fmaf(p0, ea1, wa01);
        wa02 = fmaf(p0, ea2, wa02); wa03 = fmaf(p0, ea3, wa03);
        wa10 = fmaf(p1, ea0, wa10); wa11 = fmaf(p1, ea1, wa11);
        wa12 = fmaf(p1, ea2, wa12); wa13 = fmaf(p1, ea3, wa13);
        nv0  = fmaf(p0, v0, nv0);
        nv1  = fmaf(p1, v1, nv1);
    }

    // -------- stash per-node state in LDS ----------------------------------
    wabuf[wv][j]       = wa00; wabuf[wv][64 + j]  = wa01;
    wabuf[wv][128 + j] = wa02; wabuf[wv][192 + j] = wa03;
    wabuf[wv][256 + j] = wa10; wabuf[wv][320 + j] = wa11;
    wabuf[wv][384 + j] = wa12; wabuf[wv][448 + j] = wa13;
    nvbuf[wv][j]      = nv0;
    nvbuf[wv][64 + j] = nv1;
    if (j == 0) {
        dsh[wv][0] = den0; dsh[wv][1] = den1;
        degsh[wv]  = b1 - b0;
    }
    __syncthreads();

    // -------- block-cooperative We projection ------------------------------
    // thread -> (col, node-pair): col = tid&127, pr = tid>>7 handles nodes
    // {2*pr, 2*pr+1}. We[jj][col] loaded once per block-iteration (broadcast
    // across the two pr groups), LDS reads are same-address broadcasts.
    const int col = threadIdx.x & 127;
    const int pr  = threadIdx.x >> 7;
    const int h   = col >> 6;
    const int nA  = 2 * pr, nB = 2 * pr + 1;
    const int wo  = h * 256;

    float aA = 0.f, aB = 0.f;
    #pragma unroll 8
    for (int jj = 0; jj < 256; ++jj) {
        float w = We[(size_t)jj * CH + col];
        aA = fmaf(wabuf[nA][wo + jj], w, aA);
        aB = fmaf(wabuf[nB][wo + jj], w, aB);
    }

    {
        int node = blockIdx.x * 4 + nA;
        float r = (degsh[nA] > 0) ? (nvbuf[nA][col] + aA) / dsh[nA][h] : 0.f;
        out[(size_t)node * CH + col] = r + S[(size_t)node * CH + col];
    }
    {
        int node = blockIdx.x * 4 + nB;
        float r = (degsh[nB] > 0) ? (nvbuf[nB][col] + aB) / dsh[nB][h] : 0.f;
        out[(size_t)node * CH + col] = r + S[(size_t)node * CH + col];
    }
}

extern "C" void kernel_launch(void* const* d_in, const int* in_sizes, int n_in,
                              void* d_out, int out_size, void* d_ws, size_t ws_size,
                              hipStream_t stream) {
    const float* x           = (const float*)d_in[0];
    const float* last_update = (const float*)d_in[1];
    const float* t           = (const float*)d_in[2];
    const float* msg         = (const float*)d_in[3];
    const int*   edge_index  = (const int*)d_in[4];
    const float* W_time      = (const float*)d_in[5];
    const float* b_time      = (const float*)d_in[6];
    const float* Wq = (const float*)d_in[7];
    const float* bq = (const float*)d_in[8];
    const float* Wk = (const float*)d_in[9];
    const float* bk = (const float*)d_in[10];
    const float* Wv = (const float*)d_in[11];
    const float* bv = (const float*)d_in[12];
    const float* We = (const float*)d_in[13];
    const float* Ws = (const float*)d_in[14];
    const float* bs = (const float*)d_in[15];
    float* out = (float*)d_out;

    float* ws = (float*)d_ws;
    const size_t NC = (size_t)N_NODES * CH;
    float* Q  = ws;
    float* K  = Q + NC;
    float* V  = K + NC;
    float* S  = V + NC;
    float* G  = S + NC;                            // N*512
    float* M  = G + (size_t)N_NODES * GDIM;        // 128*512
    float* gb = M + (size_t)CH * GDIM;             // 512
    int* cnt    = (int*)(gb + GDIM);
    int* base   = cnt + N_NODES;
    int* cursor = base + N_NODES + 1;
    // align edge records to 8 bytes for int2
    size_t off = (size_t)((char*)(cursor + N_NODES) - (char*)d_ws);
    off = (off + 7) & ~(size_t)7;
    int2*  sedge = (int2*)((char*)d_ws + off);
    float* srt   = (float*)(sedge + N_EDGES);

    hipMemsetAsync(cnt, 0, (size_t)N_NODES * sizeof(int), stream);

    build_M_kernel<<<CH, 256, 0, stream>>>(Wq, We, M);
    build_gbias_kernel<<<2, 256, 0, stream>>>(bq, We, gb);

    node_linear_kernel<<<(N_NODES + 63) / 64, 256, 0, stream>>>(
        x, Wq, bq, Wk, bk, Wv, bv, Ws, bs, M, gb, Q, K, V, S, G);

    hist_kernel<<<N_EDGES / 256, 256, 0, stream>>>(edge_index, cnt);
    scan_kernel<<<1, 1024, 0, stream>>>(cnt, base, cursor);
    scatter_kernel<<<N_EDGES / 256, 256, 0, stream>>>(
        edge_index, last_update, t, cursor, sedge, srt);

    gather_attn_kernel<<<N_NODES / 4, 256, 0, stream>>>(
        msg, W_time, b_time, We,
        Q, K, V, S, G, base, sedge, srt, out);
}